// Round 2
// baseline (116.938 us; speedup 1.0000x reference)
//
#include <hip/hip_runtime.h>
#include <stdint.h>
#include <stddef.h>

// Problem constants (reference: M=16, K=8192, N=8192, GROUP=128)
#define MM 16
#define KK 8192
#define NN 8192
#define GROUP_SZ 128
#define NGROUP 64            // K / GROUP
#define KPACK 1024           // K / 8 packed int32 per output row
#define NWAVE 8              // waves per block (one K/8 slice each)
#define KCH (KK / NWAVE)     // 1024 k per wave
#define GPW (KCH / GROUP_SZ) // 8 groups per wave

typedef _Float16 half8_t __attribute__((ext_vector_type(8)));
typedef _Float16 half2_t __attribute__((ext_vector_type(2)));
typedef float float4_t __attribute__((ext_vector_type(4)));
typedef uint32_t uint4_t __attribute__((ext_vector_type(4)));

// ---------------------------------------------------------------------------
// FUSED single-launch kernel: 512 blocks (one 16-col n-tile each) x 512
// threads (8 waves). Wave w owns k-slice [w*1024, (w+1)*1024) = 8 groups.
//
// Key change vs previous 2-kernel version: the MFMA A-fragment that lane L
// needs is x[m = L&15][gg*128 + quad*32 + j*8 + perm[slot]] -- for a fixed
// group that is a CONTIGUOUS 128B chunk of one x row per lane. So we build
// the f16 A-fragment in-register from direct float4 loads of x (no xf
// precompute kernel, no workspace, no cross-lane exchange, no LDS for A).
//
// Exact zero-point correction: needs sxg[m][g] = sum over group of the
// f16-ROUNDED x values, accumulated in f32 (so the +1024 offset cancels
// exactly). Computed wave-locally from the same rounded af values via
// v_dot2_f32_f16 (f16 products, exact f32 accumulate), then a cross-quad
// shuffle reduce.
//
//   qweight: one dwordx4 per lane per group (16 rows x 64B lines fully used).
//   Dequant: (d>>4j & 0x000F000F) | 0x64006400 -> fp16 (1024+q); fp32 group
//   accumulator; per-group fold of scale + exact zero-point correction.
// Cross-wave LDS reduce -> direct store with bias. No atomics, no memset.
// ---------------------------------------------------------------------------
__global__ __launch_bounds__(512) void wq_fused(
        const float* __restrict__ x,
        const int* __restrict__ qweight,
        const float* __restrict__ scales,
        const float* __restrict__ zeros,
        const float* __restrict__ bias,
        float* __restrict__ out) {
    __shared__ float red[NWAVE * 256];   // 8 KB: per-wave 16x16 partial tiles

    const int t     = threadIdx.x;
    const int w     = t >> 6;
    const int lane  = t & 63;
    const int ntile = blockIdx.x;
    const int nlo   = lane & 15;
    const int quad  = lane >> 4;
    const int n     = ntile * 16 + nlo;

    // this wave's qweight slice: row n, ints [w*128, w*128+128)
    const int* qrow = qweight + (size_t)n * KPACK + w * (KCH / 8);
    // this lane's x row-chunk base: m = nlo, k = w*1024 + quad*32 (+ g*128)
    const float4_t* xr =
        (const float4_t*)(x + (size_t)nlo * KK + w * KCH + quad * 32);

    float4_t outacc = {0.f, 0.f, 0.f, 0.f};
    const int g0 = w * GPW;

    #pragma unroll 2
    for (int g = 0; g < GPW; ++g) {
        const int gg  = g0 + g;
        const float s = scales[(size_t)gg * NN + n];
        const float z = zeros[(size_t)gg * NN + n];

        // B: 16B = 4 packed int32 = k-chunk [quad*32, +32) of this group
        const uint4_t bw = *(const uint4_t*)(qrow + g * 16 + quad * 4);

        float4_t gacc = {0.f, 0.f, 0.f, 0.f};
        float p = 0.f;   // f32 sum of f16-rounded x over this lane's 32 k
        #pragma unroll
        for (int j = 0; j < 4; ++j) {
            // 32B contiguous from x row m=nlo: k = gg*128 + quad*32 + j*8 ..+8
            const float4_t a = xr[g * 32 + 2 * j];
            const float4_t b = xr[g * 32 + 2 * j + 1];
            // fragment slot order perm = {0,4,1,5,2,6,3,7} (nibble-pair order)
            half8_t af;
            af[0] = (_Float16)a[0]; af[1] = (_Float16)b[0];
            af[2] = (_Float16)a[1]; af[3] = (_Float16)b[1];
            af[4] = (_Float16)a[2]; af[5] = (_Float16)b[2];
            af[6] = (_Float16)a[3]; af[7] = (_Float16)b[3];

            // exact f32 accumulation of the SAME rounded values
            const half2_t one = {(_Float16)1.f, (_Float16)1.f};
            half2_t q0 = {af[0], af[1]}, q1 = {af[2], af[3]};
            half2_t q2 = {af[4], af[5]}, q3 = {af[6], af[7]};
#if __has_builtin(__builtin_amdgcn_fdot2)
            p = __builtin_amdgcn_fdot2(q0, one, p, false);
            p = __builtin_amdgcn_fdot2(q1, one, p, false);
            p = __builtin_amdgcn_fdot2(q2, one, p, false);
            p = __builtin_amdgcn_fdot2(q3, one, p, false);
#else
            p += (float)af[0] + (float)af[1] + (float)af[2] + (float)af[3]
               + (float)af[4] + (float)af[5] + (float)af[6] + (float)af[7];
#endif

            const uint32_t d = bw[j];
            uint4_t bb;
            bb.x = ( d         & 0x000F000Fu) | 0x64006400u;  // nibbles (0,4)
            bb.y = ((d >> 4)   & 0x000F000Fu) | 0x64006400u;  // (1,5)
            bb.z = ((d >> 8)   & 0x000F000Fu) | 0x64006400u;  // (2,6)
            bb.w = ((d >> 12)  & 0x000F000Fu) | 0x64006400u;  // (3,7)
            gacc = __builtin_amdgcn_mfma_f32_16x16x32_f16(
                       af, __builtin_bit_cast(half8_t, bb), gacc, 0, 0, 0);
        }

        // cross-quad reduce: after these, every lane holds the full 128-k
        // group sum for its m-row class (quad bits folded out)
        p += __shfl_xor(p, 16, 64);
        p += __shfl_xor(p, 32, 64);

        const float c = z - 1024.0f * s;
        #pragma unroll
        for (int r = 0; r < 4; ++r) {
            // D-row of gacc[r] is m = quad*4 + r; fetch that m's group sum
            const float sx = __shfl(p, quad * 4 + r, 64);
            outacc[r] += s * gacc[r] + c * sx;
        }
    }

    // C/D layout: col = lane&15, row = quad*4 + r  -> red[w][row*16 + col]
    #pragma unroll
    for (int r = 0; r < 4; ++r)
        red[w * 256 + (quad * 4 + r) * 16 + nlo] = outacc[r];
    __syncthreads();

    if (t < 256) {
        const int m  = t >> 4;
        const int nn = t & 15;
        float v = bias[ntile * 16 + nn];
        #pragma unroll
        for (int ww = 0; ww < NWAVE; ++ww) v += red[ww * 256 + t];
        out[(size_t)m * NN + ntile * 16 + nn] = v;
    }
}

// ---------------------------------------------------------------------------
extern "C" void kernel_launch(void* const* d_in, const int* in_sizes, int n_in,
                              void* d_out, int out_size, void* d_ws, size_t ws_size,
                              hipStream_t stream) {
    const float* x      = (const float*)d_in[0];   // [16, 8192]
    const int*   qw     = (const int*)d_in[1];     // [8192, 1024]
    const float* scales = (const float*)d_in[2];   // [64, 8192]
    const float* zeros  = (const float*)d_in[3];   // [64, 8192]
    const float* bias   = (const float*)d_in[4];   // [8192]
    float* out = (float*)d_out;                    // [16, 8192] fp32
    (void)d_ws; (void)ws_size; (void)in_sizes; (void)n_in;

    wq_fused<<<NN / 16, 512, 0, stream>>>(x, qw, scales, zeros, bias, out);
}

// Round 3
// 97.909 us; speedup vs baseline: 1.1944x; 1.1944x over previous
//
#include <hip/hip_runtime.h>
#include <stdint.h>
#include <stddef.h>

// Problem constants (reference: M=16, K=8192, N=8192, GROUP=128)
#define MM 16
#define KK 8192
#define NN 8192
#define GROUP_SZ 128
#define NGROUP 64            // K / GROUP
#define KPACK 1024           // K / 8 packed int32 per output row
#define NWAVE 8              // waves per block (one K/8 slice each)
#define KCH (KK / NWAVE)     // 1024 k per wave
#define GPW (KCH / GROUP_SZ) // 8 groups per wave

typedef _Float16 half8_t __attribute__((ext_vector_type(8)));
typedef _Float16 half2_t __attribute__((ext_vector_type(2)));
typedef float float4_t __attribute__((ext_vector_type(4)));
typedef uint32_t uint4_t __attribute__((ext_vector_type(4)));

// XOR swizzle on the 16B-chunk index (256 chunks per wave region):
// fc bits: [7:6]=j, [5:4]=quad, [3:0]=m. Mix upper bits into [2:0] so that
// both ds_write_b128 (m uniform per 16-lane group) and ds_read_b128
// (j uniform) spread uniformly over the 8 bank-groups. Bijective (XOR of
// low bits by a function of high bits).
__device__ __forceinline__ int swz(int fc) {
    return fc ^ (((fc >> 3) ^ (fc >> 6)) & 7);
}

// ---------------------------------------------------------------------------
// FUSED single-launch kernel: 512 blocks (one 16-col n-tile) x 512 threads
// (8 waves). Wave w owns k-slice [w*1024, (w+1)*1024) = 8 groups.
//
// vs round-2: A-fragments are no longer built from per-lane scatter loads of
// x (64 lines per vector load -> latency-bound, 48us). Instead each wave
// stages its (16 rows x 128 k) group slice through a wave-PRIVATE 4KB LDS
// region:
//   - lane loads 8 consecutive k of one row (2x float4, fully coalesced:
//     the wave covers 16 rows x 512B in contiguous 512B segments)
//   - cvt to f16 in fragment slot order {0,4,1,5,2,6,3,7} = interleave of
//     the two float4s -> ONE ds_write_b128 per lane per row-quarter
//   - fragment reads are lane-consecutive ds_read_b128
//   - XOR swizzle on chunk index makes both sides bank-conflict-free
// No barriers for staging (wave-private; DS ops are in-order per wave).
// 1-group software pipeline keeps next group's global loads in flight.
// Math path identical to the validated round-2 kernel (rte f16 cvts, fdot2
// group x-sums for the exact zero-point correction, f32 group accumulators).
// ---------------------------------------------------------------------------
__global__ __launch_bounds__(512, 4) void wq_fused(
        const float* __restrict__ x,
        const int* __restrict__ qweight,
        const float* __restrict__ scales,
        const float* __restrict__ zeros,
        const float* __restrict__ bias,
        float* __restrict__ out) {
    __shared__ alignas(16) _Float16 stage[NWAVE * 2048]; // 32 KB: 4KB/wave
    __shared__ float red[NWAVE * 256];                   // 8 KB

    const int t     = threadIdx.x;
    const int w     = t >> 6;
    const int lane  = t & 63;
    const int ntile = blockIdx.x;
    const int nlo   = lane & 15;
    const int quad  = lane >> 4;
    const int n     = ntile * 16 + nlo;

    // ---- staging geometry (writer side) ----
    // lane -> (row-part lh, k-part l4): m = 4u + lh, k0 = l4*8 within group
    const int l4    = lane & 15;
    const int lh    = lane >> 4;
    const int quadw = l4 >> 2;
    const int jj    = l4 & 3;
    // this lane's global x base: row lh, k = w*1024 + l4*8
    const float* xs = x + (size_t)lh * KK + w * KCH + l4 * 8;

    half8_t* wstage = (half8_t*)(stage + w * 2048);
    int wfc[4], rfc[4];
    #pragma unroll
    for (int u = 0; u < 4; ++u)
        wfc[u] = swz(jj * 64 + quadw * 16 + 4 * u + lh);
    #pragma unroll
    for (int j = 0; j < 4; ++j)
        rfc[j] = swz(j * 64 + lane);

    // this wave's qweight slice: row n, ints [w*128, w*128+128)
    const int* qrow = qweight + (size_t)n * KPACK + w * (KCH / 8);

    float4_t outacc = {0.f, 0.f, 0.f, 0.f};
    const int g0 = w * GPW;

    // ---- software pipeline prologue: group 0 loads in flight ----
    float4_t pa[4], pb[4];
    uint4_t  bwc;
    #pragma unroll
    for (int u = 0; u < 4; ++u) {
        pa[u] = *(const float4_t*)(xs + (size_t)u * 4 * KK);
        pb[u] = *(const float4_t*)(xs + (size_t)u * 4 * KK + 4);
    }
    bwc = *(const uint4_t*)(qrow + quad * 4);

    for (int g = 0; g < GPW; ++g) {
        const int gg = g0 + g;

        // prefetch group g+1 (global loads fly under this group's work)
        float4_t na[4], nb[4];
        uint4_t  bwn;
        if (g + 1 < GPW) {
            #pragma unroll
            for (int u = 0; u < 4; ++u) {
                na[u] = *(const float4_t*)(xs + (size_t)u * 4 * KK + (g + 1) * GROUP_SZ);
                nb[u] = *(const float4_t*)(xs + (size_t)u * 4 * KK + (g + 1) * GROUP_SZ + 4);
            }
            bwn = *(const uint4_t*)(qrow + (g + 1) * 16 + quad * 4);
        }

        // cvt (rte) + fragment-ordered LDS write: slot s holds k-offset
        // perm[s] = {0,4,1,5,2,6,3,7} -> dword d = (pa[d], pb[d])
        #pragma unroll
        for (int u = 0; u < 4; ++u) {
            half8_t st;
            st[0] = (_Float16)pa[u][0]; st[1] = (_Float16)pb[u][0];
            st[2] = (_Float16)pa[u][1]; st[3] = (_Float16)pb[u][1];
            st[4] = (_Float16)pa[u][2]; st[5] = (_Float16)pb[u][2];
            st[6] = (_Float16)pa[u][3]; st[7] = (_Float16)pb[u][3];
            wstage[wfc[u]] = st;
        }

        const float s = scales[(size_t)gg * NN + n];
        const float z = zeros[(size_t)gg * NN + n];

        // fragment reads (wave-private; DS in-order per wave, compiler
        // inserts the lgkmcnt waits)
        half8_t af[4];
        #pragma unroll
        for (int j = 0; j < 4; ++j)
            af[j] = wstage[rfc[j]];

        float4_t gacc = {0.f, 0.f, 0.f, 0.f};
        float p = 0.f;   // f32 sum of f16-rounded x over this lane's 32 k
        #pragma unroll
        for (int j = 0; j < 4; ++j) {
            const half2_t one = {(_Float16)1.f, (_Float16)1.f};
            half2_t q0 = {af[j][0], af[j][1]}, q1 = {af[j][2], af[j][3]};
            half2_t q2 = {af[j][4], af[j][5]}, q3 = {af[j][6], af[j][7]};
#if __has_builtin(__builtin_amdgcn_fdot2)
            p = __builtin_amdgcn_fdot2(q0, one, p, false);
            p = __builtin_amdgcn_fdot2(q1, one, p, false);
            p = __builtin_amdgcn_fdot2(q2, one, p, false);
            p = __builtin_amdgcn_fdot2(q3, one, p, false);
#else
            p += (float)af[j][0] + (float)af[j][1] + (float)af[j][2] + (float)af[j][3]
               + (float)af[j][4] + (float)af[j][5] + (float)af[j][6] + (float)af[j][7];
#endif
            const uint32_t d = bwc[j];
            uint4_t bb;
            bb.x = ( d         & 0x000F000Fu) | 0x64006400u;  // nibbles (0,4)
            bb.y = ((d >> 4)   & 0x000F000Fu) | 0x64006400u;  // (1,5)
            bb.z = ((d >> 8)   & 0x000F000Fu) | 0x64006400u;  // (2,6)
            bb.w = ((d >> 12)  & 0x000F000Fu) | 0x64006400u;  // (3,7)
            gacc = __builtin_amdgcn_mfma_f32_16x16x32_f16(
                       af[j], __builtin_bit_cast(half8_t, bb), gacc, 0, 0, 0);
        }

        // cross-quad reduce: fold the 4 k-quads -> full 128-k group sum
        p += __shfl_xor(p, 16, 64);
        p += __shfl_xor(p, 32, 64);

        const float c = z - 1024.0f * s;
        #pragma unroll
        for (int r = 0; r < 4; ++r) {
            // D-row of gacc[r] is m = quad*4 + r; fetch that m's group sum
            const float sx = __shfl(p, quad * 4 + r, 64);
            outacc[r] += s * gacc[r] + c * sx;
        }

        if (g + 1 < GPW) {
            #pragma unroll
            for (int u = 0; u < 4; ++u) { pa[u] = na[u]; pb[u] = nb[u]; }
            bwc = bwn;
        }
    }

    // C/D layout: col = lane&15, row = quad*4 + r  -> red[w][row*16 + col]
    #pragma unroll
    for (int r = 0; r < 4; ++r)
        red[w * 256 + (quad * 4 + r) * 16 + nlo] = outacc[r];
    __syncthreads();

    if (t < 256) {
        const int m  = t >> 4;
        const int nn = t & 15;
        float v = bias[ntile * 16 + nn];
        #pragma unroll
        for (int ww = 0; ww < NWAVE; ++ww) v += red[ww * 256 + t];
        out[(size_t)m * NN + ntile * 16 + nn] = v;
    }
}

// ---------------------------------------------------------------------------
extern "C" void kernel_launch(void* const* d_in, const int* in_sizes, int n_in,
                              void* d_out, int out_size, void* d_ws, size_t ws_size,
                              hipStream_t stream) {
    const float* x      = (const float*)d_in[0];   // [16, 8192]
    const int*   qw     = (const int*)d_in[1];     // [8192, 1024]
    const float* scales = (const float*)d_in[2];   // [64, 8192]
    const float* zeros  = (const float*)d_in[3];   // [64, 8192]
    const float* bias   = (const float*)d_in[4];   // [8192]
    float* out = (float*)d_out;                    // [16, 8192] fp32
    (void)d_ws; (void)ws_size; (void)in_sizes; (void)n_in;

    wq_fused<<<NN / 16, 512, 0, stream>>>(x, qw, scales, zeros, bias, out);
}